// Round 6
// baseline (161.673 us; speedup 1.0000x reference)
//
#include <hip/hip_runtime.h>

// Self-attention (SAGAN-style): B=8, C=64, H=W=64 -> N=4096, E=C/8=8.
// Round 6: fix round 5's P-transform bug by DELETING the transform.
// ds_bpermute is pull-based: the fetched register is chosen by the SOURCE
// lane, so the selHi cndmask picked the wrong half for dest quads 1,2
// (keys 8..23 never used -> o absmax 0.81). Instead of 8 bpermutes, we
// re-map GEMM2's k-slot <-> key assignment so the C-layout registers ARE
// the B fragment: lane (quad,lm) C-regs hold keys {4q..4q+3} (s0) and
// {16+4q..16+4q+3} (s1) of query lm; B slot k=quad*8+j is defined to mean
// key pi(k) = quad*4+j (j<4) / 16+quad*4+j-4 (j>=4). V (A operand) is
// loaded with the same permutation: two dwordx2 at n0+4q and n0+16+4q.
// Zero cross-lane ops; P never leaves registers.
// Kept from round 5: raw v_exp (no guard), unconditional K loads (garbage
// k-rows x zero q-rows), fused Wo/residual epilogue, LDS-free qkv.

#define BB   8
#define CC   64
#define NPIX 4096
#define EE   8
#define BN   (BB*NPIX)        // 32768
#define YSZ  (BB*CC*NPIX)     // 2097152
#define LOG2E 1.4426950408889634f

typedef __attribute__((ext_vector_type(8))) short bf16x8;
typedef __attribute__((ext_vector_type(4))) float f32x4;

__device__ __forceinline__ unsigned short f2bf_rne(float x) {
    unsigned u = __float_as_uint(x);
    u += 0x7FFFu + ((u >> 16) & 1u);
    return (unsigned short)(u >> 16);
}
// truncation pack (p>0; ~0.4% bias cancels in softmax normalize).
__device__ __forceinline__ unsigned pack_bf_trunc(float a, float b) {
    return (__float_as_uint(a) >> 16) | (__float_as_uint(b) & 0xFFFF0000u);
}

// ---- K1: QKV projection. One proj per blockIdx.y; W via scalar pipe. ----
__global__ __launch_bounds__(256) void qkv_kernel(
    const float* __restrict__ x,
    const float* __restrict__ Wk, const float* __restrict__ bk,
    const float* __restrict__ Wq, const float* __restrict__ bq,
    const float* __restrict__ Wv, const float* __restrict__ bv,
    unsigned short* __restrict__ QT, unsigned short* __restrict__ KT,
    unsigned short* __restrict__ VT)
{
    const int proj = blockIdx.y;  // 0=Q, 1=K, 2=V
    const float* W    = (proj == 0) ? Wq : (proj == 1) ? Wk : Wv;
    const float* bias = (proj == 0) ? bq : (proj == 1) ? bk : bv;

    const int bm = blockIdx.x*256 + threadIdx.x;   // 0..BN-1
    const int b  = bm >> 12;
    const int n  = bm & (NPIX-1);
    const float* xb = x + (size_t)b*CC*NPIX + n;   // coalesced across lanes

    float xv[CC];
    #pragma unroll
    for (int c = 0; c < CC; ++c) xv[c] = xb[(size_t)c*NPIX];  // loads in flight

    float f[EE];
    #pragma unroll
    for (int e = 0; e < EE; ++e) {
        float acc = bias[e];                       // uniform -> scalar pipe
        #pragma unroll
        for (int c = 0; c < CC; ++c) acc = fmaf(W[e*CC+c], xv[c], acc);
        f[e] = acc;
    }

    if (proj == 0) {
        union { unsigned short s[8]; uint4 v; } t;
        #pragma unroll
        for (int e = 0; e < EE; ++e) t.s[e] = f2bf_rne(f[e] * LOG2E);
        *(uint4*)(QT + (size_t)bm*EE) = t.v;
    } else if (proj == 1) {
        union { unsigned short s[8]; uint4 v; } t;
        #pragma unroll
        for (int e = 0; e < EE; ++e) t.s[e] = f2bf_rne(f[e]);
        *(uint4*)(KT + (size_t)bm*EE) = t.v;
    } else {
        #pragma unroll
        for (int e = 0; e < EE; ++e)
            VT[((size_t)b*16 + e)*NPIX + n] = f2bf_rne(f[e]);  // rows 8..15 unused
    }
}

// ---- K2: flash attention + fused Wo/residual epilogue ----
// Block = one 16-query tile; 4 waves split the 4096 keys x4.
__global__ __launch_bounds__(256) void attn_fused(
    const unsigned short* __restrict__ QT, const unsigned short* __restrict__ KT,
    const unsigned short* __restrict__ VT,
    const float* __restrict__ x, const float* __restrict__ Wo,
    const float* __restrict__ bo, const float* __restrict__ gamma,
    float* __restrict__ out)
{
    __shared__ float OB[3*1024];   // waves 1..3 oacc
    __shared__ float LB[48];       // waves 1..3 l
    __shared__ float VL[16*8];     // normalized v per pixel
    __shared__ float Wos[CC*9];    // stride 9: conflict-free epilogue reads
    __shared__ float bos[CC];

    const int tid  = threadIdx.x;
    const int wave = tid >> 6, lane = tid & 63;
    const int quad = lane >> 4, lm = lane & 15;
    const int b  = blockIdx.x >> 8;
    const int m0 = (blockIdx.x & 255) * 16;

    for (int i = tid; i < CC*EE; i += 256) Wos[(i>>3)*9 + (i&7)] = Wo[i];
    if (tid < CC) bos[tid] = bo[tid];

    // B1 operand: Qpad[k=e][col=m] -> only quad0 lanes carry real rows.
    bf16x8 qf = {0,0,0,0,0,0,0,0};
    if (quad == 0)
        qf = *(const bf16x8*)(QT + (size_t)(b*NPIX + m0 + lm)*EE);

    f32x4 oacc = {0.f,0.f,0.f,0.f};
    const f32x4 zc = {0.f,0.f,0.f,0.f};
    float lacc = 0.f;

    const unsigned short* Kb = KT + (size_t)b*NPIX*EE;
    const unsigned short* Vb = VT + (size_t)b*16*NPIX;
    const int n_start = wave*1024;                 // split-K: 1024 keys/wave
    const unsigned short* kl  = Kb + (size_t)(n_start + lm)*EE;
    // V with permuted key mapping: slot j<4 -> key n0+quad*4+j,
    //                              slot j>=4 -> key n0+16+quad*4+(j-4)
    const unsigned short* vlA = Vb + (size_t)lm*NPIX + n_start + quad*4;

    #pragma unroll 4
    for (int ch = 0; ch < 32; ++ch) {
        // A1: K rows (quads 1..3 hold copies/garbage -> x zero B-rows)
        bf16x8 kf0 = *(const bf16x8*)(kl);
        bf16x8 kf1 = *(const bf16x8*)(kl + 16*EE);
        union { unsigned short s[8]; bf16x8 v; uint2 h[2]; } vf;
        vf.h[0] = *(const uint2*)(vlA);            // keys n0+4q..+3
        vf.h[1] = *(const uint2*)(vlA + 16);       // keys n0+16+4q..+3
        kl += 32*EE; vlA += 32;

        // S tiles: C-layout lane (quad,lm) reg r = S[key][query lm],
        // s0: key = 4*quad + r;  s1: key = 16 + 4*quad + r.
        f32x4 s0 = __builtin_amdgcn_mfma_f32_16x16x32_bf16(kf0, qf, zc, 0, 0, 0);
        f32x4 s1 = __builtin_amdgcn_mfma_f32_16x16x32_bf16(kf1, qf, zc, 0, 0, 0);

        float p0 = __builtin_amdgcn_exp2f(s0.x), p1 = __builtin_amdgcn_exp2f(s0.y);
        float p2 = __builtin_amdgcn_exp2f(s0.z), p3 = __builtin_amdgcn_exp2f(s0.w);
        float p4 = __builtin_amdgcn_exp2f(s1.x), p5 = __builtin_amdgcn_exp2f(s1.y);
        float p6 = __builtin_amdgcn_exp2f(s1.z), p7 = __builtin_amdgcn_exp2f(s1.w);
        lacc += ((p0+p1)+(p2+p3)) + ((p4+p5)+(p6+p7));

        // B2 fragment IS the C-layout regs under the permuted key map:
        // slot k=quad*8+j: j=0..3 -> p0..p3 (keys 4q+j), j=4..7 -> p4..p7.
        union { unsigned u[4]; bf16x8 v; } pu;
        pu.u[0] = pack_bf_trunc(p0, p1);
        pu.u[1] = pack_bf_trunc(p2, p3);
        pu.u[2] = pack_bf_trunc(p4, p5);
        pu.u[3] = pack_bf_trunc(p6, p7);
        oacc = __builtin_amdgcn_mfma_f32_16x16x32_bf16(vf.v, pu.v, oacc, 0, 0, 0);
    }

    // l[m]: lanes lm, lm+16, lm+32, lm+48 hold disjoint key-partials of query lm
    lacc += __shfl_xor(lacc, 16);
    lacc += __shfl_xor(lacc, 32);

    if (wave != 0) {
        *(f32x4*)(OB + (size_t)(wave-1)*1024 + lane*4) = oacc;
        if (lane < 16) LB[(wave-1)*16 + lane] = lacc;
    }
    __syncthreads();
    if (wave == 0) {
        f32x4 o = oacc;
        #pragma unroll
        for (int w = 0; w < 3; ++w)
            o += *(f32x4*)(OB + (size_t)w*1024 + lane*4);
        float lt  = lacc + LB[lm] + LB[16+lm] + LB[32+lm];
        float inv = 1.f / lt;
        if (quad < 2) {                            // rows e = quad*4+reg in 0..7
            f32x4 st = { o.x*inv, o.y*inv, o.z*inv, o.w*inv };
            *(f32x4*)(VL + lm*8 + quad*4) = st;
        }
    }
    __syncthreads();

    // Fused epilogue: 16 px x 64 ch over 256 threads (4 ch each).
    const float g  = gamma[0];
    const int   px = tid & 15;
    const int   cg = tid >> 4;                     // 0..15
    const size_t base = (size_t)b*CC*NPIX + (m0 + px);
    float v[EE];
    #pragma unroll
    for (int e = 0; e < EE; ++e) v[e] = VL[px*8 + e];
    #pragma unroll
    for (int i = 0; i < 4; ++i) {
        const int c = cg*4 + i;
        float o = bos[c];
        #pragma unroll
        for (int e = 0; e < EE; ++e) o += Wos[c*9 + e] * v[e];
        out[(size_t)YSZ + base + (size_t)c*NPIX] = o;
        out[base + (size_t)c*NPIX] = g*o + x[base + (size_t)c*NPIX];
    }
    if (blockIdx.x == 0 && tid == 0) out[2*(size_t)YSZ] = g;  // gamma passthrough
}

extern "C" void kernel_launch(void* const* d_in, const int* in_sizes, int n_in,
                              void* d_out, int out_size, void* d_ws, size_t ws_size,
                              hipStream_t stream) {
    const float* x     = (const float*)d_in[0];
    const float* Wk    = (const float*)d_in[1];
    const float* bk    = (const float*)d_in[2];
    const float* Wq    = (const float*)d_in[3];
    const float* bq    = (const float*)d_in[4];
    const float* Wv    = (const float*)d_in[5];
    const float* bv    = (const float*)d_in[6];
    const float* Wo    = (const float*)d_in[7];
    const float* bo    = (const float*)d_in[8];
    const float* gamma = (const float*)d_in[9];
    float* out = (float*)d_out;

    // ws: QT(512KB) | KT(512KB) | VT(1MB bf16 [b][16][N], rows 8..15 never
    // written -- poison rows only affect discarded C rows) = 2MB
    unsigned short* QT = (unsigned short*)d_ws;
    unsigned short* KT = QT + (size_t)BN*EE;
    unsigned short* VT = KT + (size_t)BN*EE;

    qkv_kernel<<<dim3(BN/256, 3), 256, 0, stream>>>(x, Wk, bk, Wq, bq, Wv, bv, QT, KT, VT);
    attn_fused<<<BB*256, 256, 0, stream>>>(QT, KT, VT, x, Wo, bo, gamma, out);
}

// Round 7
// 131.249 us; speedup vs baseline: 1.2318x; 1.2318x over previous
//
#include <hip/hip_runtime.h>

// Self-attention (SAGAN-style): B=8, C=64, H=W=64 -> N=4096, E=C/8=8.
// Round 7: fix round 6's L1/texture-issue bound. r6 loaded K on all 64 lanes
// (1KB/instr = 16 L1-cyc); with 32 waves/CU that outran the CU's L1 (~48
// L1-cyc demand vs ~56 VALU-cyc per chunk) -> VALUBusy 24%. Changes:
// (a) K loads exec-masked to quad0 (256B/instr); quads 1..3 keep stale regs
//     which multiply qf's zero rows -> zero-init ONCE, no per-chunk v_movs.
// (b) 2 query-tiles per wave (32 q/block, grid 1024): same K/V loads feed
//     2x compute (6 MFMA + 16 exp per chunk) -> L1 ~24 cyc vs VALU ~112 cyc.
// (c) register prefetch of next chunk's K/V before computing current.
// Kept: permuted-key GEMM2 (P stays in registers; verified r6), raw v_exp,
// fused Wo/residual epilogue, LDS-free qkv.

#define BB   8
#define CC   64
#define NPIX 4096
#define EE   8
#define BN   (BB*NPIX)        // 32768
#define YSZ  (BB*CC*NPIX)     // 2097152
#define LOG2E 1.4426950408889634f

typedef __attribute__((ext_vector_type(8))) short bf16x8;
typedef __attribute__((ext_vector_type(4))) float f32x4;

__device__ __forceinline__ unsigned short f2bf_rne(float x) {
    unsigned u = __float_as_uint(x);
    u += 0x7FFFu + ((u >> 16) & 1u);
    return (unsigned short)(u >> 16);
}
__device__ __forceinline__ unsigned pack_bf_trunc(float a, float b) {
    return (__float_as_uint(a) >> 16) | (__float_as_uint(b) & 0xFFFF0000u);
}

// ---- K1: QKV projection (unchanged from round 6; correct) ----
__global__ __launch_bounds__(256) void qkv_kernel(
    const float* __restrict__ x,
    const float* __restrict__ Wk, const float* __restrict__ bk,
    const float* __restrict__ Wq, const float* __restrict__ bq,
    const float* __restrict__ Wv, const float* __restrict__ bv,
    unsigned short* __restrict__ QT, unsigned short* __restrict__ KT,
    unsigned short* __restrict__ VT)
{
    const int proj = blockIdx.y;  // 0=Q, 1=K, 2=V
    const float* W    = (proj == 0) ? Wq : (proj == 1) ? Wk : Wv;
    const float* bias = (proj == 0) ? bq : (proj == 1) ? bk : bv;

    const int bm = blockIdx.x*256 + threadIdx.x;
    const int b  = bm >> 12;
    const int n  = bm & (NPIX-1);
    const float* xb = x + (size_t)b*CC*NPIX + n;

    float xv[CC];
    #pragma unroll
    for (int c = 0; c < CC; ++c) xv[c] = xb[(size_t)c*NPIX];

    float f[EE];
    #pragma unroll
    for (int e = 0; e < EE; ++e) {
        float acc = bias[e];
        #pragma unroll
        for (int c = 0; c < CC; ++c) acc = fmaf(W[e*CC+c], xv[c], acc);
        f[e] = acc;
    }

    if (proj == 0) {
        union { unsigned short s[8]; uint4 v; } t;
        #pragma unroll
        for (int e = 0; e < EE; ++e) t.s[e] = f2bf_rne(f[e] * LOG2E);
        *(uint4*)(QT + (size_t)bm*EE) = t.v;
    } else if (proj == 1) {
        union { unsigned short s[8]; uint4 v; } t;
        #pragma unroll
        for (int e = 0; e < EE; ++e) t.s[e] = f2bf_rne(f[e]);
        *(uint4*)(KT + (size_t)bm*EE) = t.v;
    } else {
        #pragma unroll
        for (int e = 0; e < EE; ++e)
            VT[((size_t)b*16 + e)*NPIX + n] = f2bf_rne(f[e]);
    }
}

// ---- K2: flash attention, 2 query-tiles/wave + fused epilogue ----
// Block = 32 queries; 4 waves split the 4096 keys x4. Grid = 8*128 = 1024.
__global__ __launch_bounds__(256) void attn_fused(
    const unsigned short* __restrict__ QT, const unsigned short* __restrict__ KT,
    const unsigned short* __restrict__ VT,
    const float* __restrict__ x, const float* __restrict__ Wo,
    const float* __restrict__ bo, const float* __restrict__ gamma,
    float* __restrict__ out)
{
    __shared__ float OB[3*2*256];  // waves 1..3 x {A,B} x 64 lanes x f32x4
    __shared__ float LB[3*2*16];   // waves 1..3 x {A,B} x 16 queries
    __shared__ float VL[32*8];     // normalized v per pixel
    __shared__ float Wos[CC*9];    // stride 9: conflict-free epilogue reads
    __shared__ float bos[CC];

    const int tid  = threadIdx.x;
    const int wave = tid >> 6, lane = tid & 63;
    const int quad = lane >> 4, lm = lane & 15;
    const int b  = blockIdx.x >> 7;
    const int m0 = (blockIdx.x & 127) * 32;

    for (int i = tid; i < CC*EE; i += 256) Wos[(i>>3)*9 + (i&7)] = Wo[i];
    if (tid < CC) bos[tid] = bo[tid];

    // B1 operands: only quad0 lanes carry real q rows; others stay zero.
    bf16x8 qfA = {0,0,0,0,0,0,0,0}, qfB = {0,0,0,0,0,0,0,0};
    if (quad == 0) {
        qfA = *(const bf16x8*)(QT + (size_t)(b*NPIX + m0 + lm)*EE);
        qfB = *(const bf16x8*)(QT + (size_t)(b*NPIX + m0 + 16 + lm)*EE);
    }

    f32x4 oaccA = {0.f,0.f,0.f,0.f}, oaccB = {0.f,0.f,0.f,0.f};
    const f32x4 zc = {0.f,0.f,0.f,0.f};
    float laccA = 0.f, laccB = 0.f;

    const unsigned short* Kb = KT + (size_t)b*NPIX*EE;
    const unsigned short* Vb = VT + (size_t)b*16*NPIX;
    const int n_start = wave*1024;                 // split-K: 1024 keys/wave
    const unsigned short* kl  = Kb + (size_t)(n_start + lm)*EE;
    const unsigned short* vlA = Vb + (size_t)lm*NPIX + n_start + quad*4;

    // prefetch chunk 0; K masked to quad0 (quads 1..3 hold zeros/stale ->
    // multiplied by qf zero rows, harmless)
    bf16x8 kf0n = {0,0,0,0,0,0,0,0}, kf1n = {0,0,0,0,0,0,0,0};
    if (quad == 0) {
        kf0n = *(const bf16x8*)(kl);
        kf1n = *(const bf16x8*)(kl + 16*EE);
    }
    uint2 vf0n = *(const uint2*)(vlA);
    uint2 vf1n = *(const uint2*)(vlA + 16);

    for (int ch = 0; ch < 32; ++ch) {
        bf16x8 kf0 = kf0n, kf1 = kf1n;
        union { unsigned short s[8]; bf16x8 v; uint2 h[2]; } vf;
        vf.h[0] = vf0n; vf.h[1] = vf1n;
        kl += 32*EE; vlA += 32;
        if (ch < 31) {                             // prefetch next chunk
            if (quad == 0) {
                kf0n = *(const bf16x8*)(kl);
                kf1n = *(const bf16x8*)(kl + 16*EE);
            }
            vf0n = *(const uint2*)(vlA);
            vf1n = *(const uint2*)(vlA + 16);
        }

        f32x4 s0a = __builtin_amdgcn_mfma_f32_16x16x32_bf16(kf0, qfA, zc, 0, 0, 0);
        f32x4 s1a = __builtin_amdgcn_mfma_f32_16x16x32_bf16(kf1, qfA, zc, 0, 0, 0);
        f32x4 s0b = __builtin_amdgcn_mfma_f32_16x16x32_bf16(kf0, qfB, zc, 0, 0, 0);
        f32x4 s1b = __builtin_amdgcn_mfma_f32_16x16x32_bf16(kf1, qfB, zc, 0, 0, 0);

        float a0 = __builtin_amdgcn_exp2f(s0a.x), a1 = __builtin_amdgcn_exp2f(s0a.y);
        float a2 = __builtin_amdgcn_exp2f(s0a.z), a3 = __builtin_amdgcn_exp2f(s0a.w);
        float a4 = __builtin_amdgcn_exp2f(s1a.x), a5 = __builtin_amdgcn_exp2f(s1a.y);
        float a6 = __builtin_amdgcn_exp2f(s1a.z), a7 = __builtin_amdgcn_exp2f(s1a.w);
        float b0 = __builtin_amdgcn_exp2f(s0b.x), b1 = __builtin_amdgcn_exp2f(s0b.y);
        float b2 = __builtin_amdgcn_exp2f(s0b.z), b3 = __builtin_amdgcn_exp2f(s0b.w);
        float b4 = __builtin_amdgcn_exp2f(s1b.x), b5 = __builtin_amdgcn_exp2f(s1b.y);
        float b6 = __builtin_amdgcn_exp2f(s1b.z), b7 = __builtin_amdgcn_exp2f(s1b.w);
        laccA += ((a0+a1)+(a2+a3)) + ((a4+a5)+(a6+a7));
        laccB += ((b0+b1)+(b2+b3)) + ((b4+b5)+(b6+b7));

        // B2 fragments ARE the C-layout regs under the permuted key map
        // (slot k=quad*8+j -> key quad*4+j (j<4) / 16+quad*4+j-4 (j>=4)),
        // matching the vlA/vlA+16 V load permutation. Verified round 6.
        union { unsigned u[4]; bf16x8 v; } puA, puB;
        puA.u[0] = pack_bf_trunc(a0, a1); puA.u[1] = pack_bf_trunc(a2, a3);
        puA.u[2] = pack_bf_trunc(a4, a5); puA.u[3] = pack_bf_trunc(a6, a7);
        puB.u[0] = pack_bf_trunc(b0, b1); puB.u[1] = pack_bf_trunc(b2, b3);
        puB.u[2] = pack_bf_trunc(b4, b5); puB.u[3] = pack_bf_trunc(b6, b7);
        oaccA = __builtin_amdgcn_mfma_f32_16x16x32_bf16(vf.v, puA.v, oaccA, 0, 0, 0);
        oaccB = __builtin_amdgcn_mfma_f32_16x16x32_bf16(vf.v, puB.v, oaccB, 0, 0, 0);
    }

    // per-query l: lanes lm,lm+16,lm+32,lm+48 hold disjoint key-partials
    laccA += __shfl_xor(laccA, 16); laccA += __shfl_xor(laccA, 32);
    laccB += __shfl_xor(laccB, 16); laccB += __shfl_xor(laccB, 32);

    if (wave != 0) {
        *(f32x4*)(OB + ((size_t)(wave-1)*2 + 0)*256 + lane*4) = oaccA;
        *(f32x4*)(OB + ((size_t)(wave-1)*2 + 1)*256 + lane*4) = oaccB;
        if (lane < 16) {
            LB[((wave-1)*2 + 0)*16 + lane] = laccA;
            LB[((wave-1)*2 + 1)*16 + lane] = laccB;
        }
    }
    __syncthreads();
    if (wave == 0) {
        f32x4 oA = oaccA, oB = oaccB;
        float lA = laccA, lB = laccB;
        #pragma unroll
        for (int w = 0; w < 3; ++w) {
            oA += *(f32x4*)(OB + ((size_t)w*2 + 0)*256 + lane*4);
            oB += *(f32x4*)(OB + ((size_t)w*2 + 1)*256 + lane*4);
            lA += LB[(w*2 + 0)*16 + lm];
            lB += LB[(w*2 + 1)*16 + lm];
        }
        float invA = 1.f / lA, invB = 1.f / lB;
        if (quad < 2) {                            // rows e = quad*4+reg in 0..7
            f32x4 sA = { oA.x*invA, oA.y*invA, oA.z*invA, oA.w*invA };
            f32x4 sB = { oB.x*invB, oB.y*invB, oB.z*invB, oB.w*invB };
            *(f32x4*)(VL + lm*8 + quad*4)        = sA;
            *(f32x4*)(VL + (16 + lm)*8 + quad*4) = sB;
        }
    }
    __syncthreads();

    // Fused epilogue: 32 px x 64 ch over 256 threads (8 ch each).
    const float g  = gamma[0];
    const int   px = tid & 31;
    const int   cg = tid >> 5;                     // 0..7
    const size_t base = (size_t)b*CC*NPIX + (m0 + px);
    float v[EE];
    #pragma unroll
    for (int e = 0; e < EE; ++e) v[e] = VL[px*8 + e];
    #pragma unroll
    for (int i = 0; i < 8; ++i) {
        const int c = cg*8 + i;
        float o = bos[c];
        #pragma unroll
        for (int e = 0; e < EE; ++e) o += Wos[c*9 + e] * v[e];
        out[(size_t)YSZ + base + (size_t)c*NPIX] = o;
        out[base + (size_t)c*NPIX] = g*o + x[base + (size_t)c*NPIX];
    }
    if (blockIdx.x == 0 && tid == 0) out[2*(size_t)YSZ] = g;  // gamma passthrough
}

extern "C" void kernel_launch(void* const* d_in, const int* in_sizes, int n_in,
                              void* d_out, int out_size, void* d_ws, size_t ws_size,
                              hipStream_t stream) {
    const float* x     = (const float*)d_in[0];
    const float* Wk    = (const float*)d_in[1];
    const float* bk    = (const float*)d_in[2];
    const float* Wq    = (const float*)d_in[3];
    const float* bq    = (const float*)d_in[4];
    const float* Wv    = (const float*)d_in[5];
    const float* bv    = (const float*)d_in[6];
    const float* Wo    = (const float*)d_in[7];
    const float* bo    = (const float*)d_in[8];
    const float* gamma = (const float*)d_in[9];
    float* out = (float*)d_out;

    // ws: QT(512KB) | KT(512KB) | VT(1MB bf16 [b][16][N], rows 8..15 never
    // written -- poison rows only affect discarded C rows) = 2MB
    unsigned short* QT = (unsigned short*)d_ws;
    unsigned short* KT = QT + (size_t)BN*EE;
    unsigned short* VT = KT + (size_t)BN*EE;

    qkv_kernel<<<dim3(BN/256, 3), 256, 0, stream>>>(x, Wk, bk, Wq, bq, Wv, bv, QT, KT, VT);
    attn_fused<<<BB*128, 256, 0, stream>>>(QT, KT, VT, x, Wo, bo, gamma, out);
}